// Round 1
// baseline (217.787 us; speedup 1.0000x reference)
//
#include <hip/hip_runtime.h>

// GradientLoss: sum_c mean( (conv3d_c(x) - conv3d_c(y))^2 ), c in {d,h,w} Sobel dirs.
// conv is linear -> conv(x)-conv(y) = conv(x-y). Filters separable:
//   fx = g_d (x) s_h (x) s_w ; fy = s_d (x) g_h (x) s_w ; fz = s_d (x) s_h (x) g_w
// with s=[1,2,1], g=[1,0,-1]. SAME zero padding. Squared output -> kernel flip
// irrelevant.

#define N_  2
#define D_  160
#define H_  192
#define W_  224

#define TW  64   // tile width  (threads.x)
#define TH  16   // tile height (4 rows per thread.y)
#define TD  32   // d-chunk per block

constexpr int LROWS = TH + 2;   // 18
constexpr int LCOLS = TW + 2;   // 66
constexpr float SCALE = 1.0f / ((float)N_ * D_ * H_ * W_);  // mean over N,D,H,W

__global__ __launch_bounds__(256, 2)
void grad_loss_kernel(const float* __restrict__ x, const float* __restrict__ y,
                      float* __restrict__ out) {
    __shared__ float plane[2][LROWS][LCOLS];
    __shared__ float wsum[4];

    const int tx  = threadIdx.x;          // 0..63 -> w offset
    const int ty  = threadIdx.y;          // 0..3  -> 4 h-rows each
    const int tid = ty * 64 + tx;

    const int w0 = blockIdx.x * TW;
    const int h0 = blockIdx.y * TH;
    const int nchunks = D_ / TD;          // 5
    const int n  = blockIdx.z / nchunks;
    const int d0 = (blockIdx.z % nchunks) * TD;

    const size_t base = (size_t)n * D_ * H_ * W_;
    const bool active = (w0 + tx) < W_;   // W=224 = 3.5 * 64 -> last tile partial

    // rolling per-plane stencil results, 3-plane ring, 4 rows per thread
    float t0r[3][4], t1r[3][4], t2r[3][4];
    float acc = 0.f;

    const int rbase = 4 * ty;  // thread's first output row (local); LDS rows rbase..rbase+5

    for (int p = d0 - 1, it = 0; p <= d0 + TD; ++p, ++it) {
        // ---- stage plane p (zero-padded) of v = x - y into LDS ----
        float (*buf)[LCOLS] = plane[it & 1];
        const bool pin = (p >= 0) && (p < D_);
        for (int idx = tid; idx < LROWS * LCOLS; idx += 256) {
            int row = idx / LCOLS;
            int col = idx - row * LCOLS;
            int gh = h0 - 1 + row;
            int gw = w0 - 1 + col;
            float v = 0.f;
            if (pin && (unsigned)gh < (unsigned)H_ && (unsigned)gw < (unsigned)W_) {
                size_t off = base + ((size_t)p * H_ + gh) * W_ + gw;
                v = x[off] - y[off];
            }
            buf[row][col] = v;
        }
        __syncthreads();
        // single barrier per iter is safe: buf[(it+1)&1] written next iter was
        // last read at iter it-1, and barrier at iter it orders that.

        // ---- in-plane stencils for this thread's 6 LDS rows ----
        const int slot = it % 3;
        float sw[6], gw_[6];
        #pragma unroll
        for (int r = 0; r < 6; ++r) {
            float a = buf[rbase + r][tx];
            float b = buf[rbase + r][tx + 1];
            float c = buf[rbase + r][tx + 2];
            sw[r] = a + 2.f * b + c;   // s_w
            gw_[r] = a - c;            // g_w
        }
        #pragma unroll
        for (int j = 0; j < 4; ++j) {
            t0r[slot][j] = sw[j] + 2.f * sw[j + 1] + sw[j + 2];   // s_h s_w
            t1r[slot][j] = sw[j] - sw[j + 2];                     // g_h s_w
            t2r[slot][j] = gw_[j] + 2.f * gw_[j + 1] + gw_[j + 2];// s_h g_w
        }

        // ---- finish d-axis for center plane c = p-1 ----
        if (it >= 2 && active) {
            const int s0 = (it - 2) % 3;   // plane c-1
            const int s1 = (it - 1) % 3;   // plane c
            const int s2 = slot;           // plane c+1
            #pragma unroll
            for (int j = 0; j < 4; ++j) {
                float gx = t0r[s0][j] - t0r[s2][j];                       // g_d s_h s_w
                float gy = t1r[s0][j] + 2.f * t1r[s1][j] + t1r[s2][j];    // s_d g_h s_w
                float gz = t2r[s0][j] + 2.f * t2r[s1][j] + t2r[s2][j];    // s_d s_h g_w
                acc = fmaf(gx, gx, acc);
                acc = fmaf(gy, gy, acc);
                acc = fmaf(gz, gz, acc);
            }
        }
    }

    // ---- block reduction: wave64 shuffle, then across 4 waves ----
    #pragma unroll
    for (int off = 32; off > 0; off >>= 1)
        acc += __shfl_down(acc, off, 64);
    if (tx == 0) wsum[ty] = acc;
    __syncthreads();
    if (tid == 0) {
        float s = (wsum[0] + wsum[1]) + (wsum[2] + wsum[3]);
        atomicAdd(out, s * SCALE);
    }
}

extern "C" void kernel_launch(void* const* d_in, const int* in_sizes, int n_in,
                              void* d_out, int out_size, void* d_ws, size_t ws_size,
                              hipStream_t stream) {
    const float* x = (const float*)d_in[0];
    const float* y = (const float*)d_in[1];
    float* out = (float*)d_out;

    // d_out is poisoned before every timed launch; we accumulate with atomics,
    // so zero it first (async memset is graph-capture safe).
    hipMemsetAsync(out, 0, sizeof(float), stream);

    dim3 block(TW, 256 / TW);                         // 64 x 4
    dim3 grid((W_ + TW - 1) / TW,                     // 4
              H_ / TH,                                // 12
              N_ * (D_ / TD));                        // 10
    grad_loss_kernel<<<grid, block, 0, stream>>>(x, y, out);
}

// Round 2
// 198.129 us; speedup vs baseline: 1.0992x; 1.0992x over previous
//
#include <hip/hip_runtime.h>

// GradientLoss: sum_c mean( (conv3d_c(x) - conv3d_c(y))^2 ), c in {d,h,w} Sobel dirs.
// conv linear -> conv(x)-conv(y) = conv(x-y). Separable filters:
//   fx = g_d (x) s_h (x) s_w ; fy = s_d (x) g_h (x) s_w ; fz = s_d (x) s_h (x) g_w
// with s=[1,2,1], g=[1,0,-1]. SAME zero padding; squared output -> flip irrelevant.
//
// R1: TD 32->8 (1920 blocks, ~7.5 blocks/CU) + float4 staging (aligned 72-wide
// rows; W%4==0 so every 4-aligned chunk is fully in- or out-of-range).

#define N_  2
#define D_  160
#define H_  192
#define W_  224

#define TW  64   // tile width  (threads.x)
#define TH  16   // tile height (4 rows per thread.y)
#define TD  8    // d-chunk per block

constexpr int LROWS = TH + 2;   // 18
constexpr int LCW   = 18;       // float4 chunks per row
constexpr int LCOLS = LCW * 4;  // 72 floats per row (cols 3..68 used by stencil)
constexpr float SCALE = 1.0f / ((float)N_ * D_ * H_ * W_);

__global__ __launch_bounds__(256, 8)
void grad_loss_kernel(const float* __restrict__ x, const float* __restrict__ y,
                      float* __restrict__ out) {
    __shared__ float plane[2][LROWS][LCOLS];
    __shared__ float wsum[4];

    const int tx  = threadIdx.x;          // 0..63 -> w offset
    const int ty  = threadIdx.y;          // 0..3  -> 4 h-rows each
    const int tid = ty * 64 + tx;

    const int w0 = blockIdx.x * TW;
    const int h0 = blockIdx.y * TH;
    const int nchunks = D_ / TD;          // 20
    const int n  = blockIdx.z / nchunks;
    const int d0 = (blockIdx.z % nchunks) * TD;

    const size_t base = (size_t)n * D_ * H_ * W_;
    const bool active = (w0 + tx) < W_;   // last w-tile is half-empty (224 = 3.5*64)

    float t0r[3][4], t1r[3][4], t2r[3][4];
    float acc = 0.f;

    const int rbase = 4 * ty;  // thread's first LDS row; uses rows rbase..rbase+5

    for (int p = d0 - 1, it = 0; p <= d0 + TD; ++p, ++it) {
        // ---- stage plane p of v = x - y into LDS, float4 chunks ----
        float (*buf)[LCOLS] = plane[it & 1];
        const bool pin = (p >= 0) && (p < D_);
        for (int idx = tid; idx < LROWS * LCW; idx += 256) {   // 324 chunks, <=2 iters
            int row = idx / LCW;
            int ci  = idx - row * LCW;
            int gh  = h0 - 1 + row;
            int gw0 = w0 - 4 + 4 * ci;                         // 16B aligned
            float4 v = make_float4(0.f, 0.f, 0.f, 0.f);
            if (pin && (unsigned)gh < (unsigned)H_ && (unsigned)gw0 < (unsigned)W_) {
                size_t off = base + ((size_t)p * H_ + gh) * W_ + gw0;
                float4 a = *(const float4*)(x + off);
                float4 b = *(const float4*)(y + off);
                v = make_float4(a.x - b.x, a.y - b.y, a.z - b.z, a.w - b.w);
            }
            *(float4*)&buf[row][4 * ci] = v;
        }
        __syncthreads();
        // one barrier/iter is safe with double buffer: barrier at it+1 orders
        // iteration-it reads of buf[it&1] before iteration-(it+2) writes.

        // ---- in-plane stencils for this thread's 6 LDS rows ----
        const int slot = it % 3;
        float sw[6], gw_[6];
        #pragma unroll
        for (int r = 0; r < 6; ++r) {
            float a = buf[rbase + r][tx + 3];
            float b = buf[rbase + r][tx + 4];
            float c = buf[rbase + r][tx + 5];
            sw[r]  = a + 2.f * b + c;   // s_w
            gw_[r] = a - c;             // g_w
        }
        #pragma unroll
        for (int j = 0; j < 4; ++j) {
            t0r[slot][j] = sw[j] + 2.f * sw[j + 1] + sw[j + 2];    // s_h s_w
            t1r[slot][j] = sw[j] - sw[j + 2];                      // g_h s_w
            t2r[slot][j] = gw_[j] + 2.f * gw_[j + 1] + gw_[j + 2]; // s_h g_w
        }

        // ---- finish d-axis for center plane c = p-1 ----
        if (it >= 2 && active) {
            const int s0 = (it - 2) % 3;
            const int s1 = (it - 1) % 3;
            const int s2 = slot;
            #pragma unroll
            for (int j = 0; j < 4; ++j) {
                float gx = t0r[s0][j] - t0r[s2][j];                    // g_d s_h s_w
                float gy = t1r[s0][j] + 2.f * t1r[s1][j] + t1r[s2][j]; // s_d g_h s_w
                float gz = t2r[s0][j] + 2.f * t2r[s1][j] + t2r[s2][j]; // s_d s_h g_w
                acc = fmaf(gx, gx, acc);
                acc = fmaf(gy, gy, acc);
                acc = fmaf(gz, gz, acc);
            }
        }
    }

    // ---- block reduction ----
    #pragma unroll
    for (int off = 32; off > 0; off >>= 1)
        acc += __shfl_down(acc, off, 64);
    if (tx == 0) wsum[ty] = acc;
    __syncthreads();
    if (tid == 0) {
        float s = (wsum[0] + wsum[1]) + (wsum[2] + wsum[3]);
        atomicAdd(out, s * SCALE);
    }
}

extern "C" void kernel_launch(void* const* d_in, const int* in_sizes, int n_in,
                              void* d_out, int out_size, void* d_ws, size_t ws_size,
                              hipStream_t stream) {
    const float* x = (const float*)d_in[0];
    const float* y = (const float*)d_in[1];
    float* out = (float*)d_out;

    hipMemsetAsync(out, 0, sizeof(float), stream);

    dim3 block(TW, 256 / TW);                 // 64 x 4
    dim3 grid((W_ + TW - 1) / TW,             // 4
              H_ / TH,                        // 12
              N_ * (D_ / TD));                // 40
    grad_loss_kernel<<<grid, block, 0, stream>>>(x, y, out);
}

// Round 3
// 152.156 us; speedup vs baseline: 1.4313x; 1.3021x over previous
//
#include <hip/hip_runtime.h>

// GradientLoss: sum_c mean( (conv3d_c(x) - conv3d_c(y))^2 ), c in {d,h,w} Sobel dirs.
// conv linear -> conv(x)-conv(y) = conv(x-y). Separable filters:
//   fx = g_d (x) s_h (x) s_w ; fy = s_d (x) g_h (x) s_w ; fz = s_d (x) s_h (x) g_w
// with s=[1,2,1], g=[1,0,-1]. SAME zero padding; squared output -> flip irrelevant.
//
// R2: kill scratch. R1's t*[slot] ring buffers (dynamic idx) were demoted to
// scratch -> 152 MB HBM writes. Replace with statically-indexed 2-plane history
// registers rotated by copy. launch_bounds (256,6) so the ~60-70 VGPR state
// isn't forced to spill.

#define N_  2
#define D_  160
#define H_  192
#define W_  224

#define TW  64   // tile width  (threads.x)
#define TH  16   // tile height (4 rows per thread.y)
#define TD  8    // d-chunk per block

constexpr int LROWS = TH + 2;   // 18
constexpr int LCW   = 18;       // float4 chunks per row
constexpr int LCOLS = LCW * 4;  // 72 floats per row (cols 3..68 used by stencil)
constexpr float SCALE = 1.0f / ((float)N_ * D_ * H_ * W_);

__global__ __launch_bounds__(256, 6)
void grad_loss_kernel(const float* __restrict__ x, const float* __restrict__ y,
                      float* __restrict__ out) {
    __shared__ float plane[2][LROWS][LCOLS];
    __shared__ float wsum[4];

    const int tx  = threadIdx.x;          // 0..63 -> w offset
    const int ty  = threadIdx.y;          // 0..3  -> 4 h-rows each
    const int tid = ty * 64 + tx;

    const int w0 = blockIdx.x * TW;
    const int h0 = blockIdx.y * TH;
    const int nchunks = D_ / TD;          // 20
    const int n  = blockIdx.z / nchunks;
    const int d0 = (blockIdx.z % nchunks) * TD;

    const size_t base = (size_t)n * D_ * H_ * W_;
    const bool active = (w0 + tx) < W_;   // last w-tile is half-empty (224 = 3.5*64)

    // statically-indexed 2-plane history (plane p-2 = a, plane p-1 = b)
    float a0[4], a1[4], a2[4];
    float b0[4], b1[4], b2[4];
    float acc = 0.f;

    const int rbase = 4 * ty;  // thread's first LDS row; uses rows rbase..rbase+5

    for (int p = d0 - 1, it = 0; p <= d0 + TD; ++p, ++it) {
        // ---- stage plane p of v = x - y into LDS, float4 chunks ----
        float (*buf)[LCOLS] = plane[it & 1];
        const bool pin = (p >= 0) && (p < D_);
        for (int idx = tid; idx < LROWS * LCW; idx += 256) {   // 324 chunks, <=2 iters
            int row = idx / LCW;
            int ci  = idx - row * LCW;
            int gh  = h0 - 1 + row;
            int gw0 = w0 - 4 + 4 * ci;                         // 16B aligned
            float4 v = make_float4(0.f, 0.f, 0.f, 0.f);
            if (pin && (unsigned)gh < (unsigned)H_ && (unsigned)gw0 < (unsigned)W_) {
                size_t off = base + ((size_t)p * H_ + gh) * W_ + gw0;
                float4 a = *(const float4*)(x + off);
                float4 b = *(const float4*)(y + off);
                v = make_float4(a.x - b.x, a.y - b.y, a.z - b.z, a.w - b.w);
            }
            *(float4*)&buf[row][4 * ci] = v;
        }
        __syncthreads();
        // one barrier/iter is safe with double buffer: barrier at it+1 orders
        // iteration-it reads of buf[it&1] before iteration-(it+2) writes.

        // ---- in-plane stencils for this thread's 6 LDS rows (new plane) ----
        float sw[6], gw_[6];
        #pragma unroll
        for (int r = 0; r < 6; ++r) {
            float a = buf[rbase + r][tx + 3];
            float b = buf[rbase + r][tx + 4];
            float c = buf[rbase + r][tx + 5];
            sw[r]  = a + 2.f * b + c;   // s_w
            gw_[r] = a - c;             // g_w
        }
        float n0[4], n1[4], n2[4];
        #pragma unroll
        for (int j = 0; j < 4; ++j) {
            n0[j] = sw[j] + 2.f * sw[j + 1] + sw[j + 2];    // s_h s_w
            n1[j] = sw[j] - sw[j + 2];                      // g_h s_w
            n2[j] = gw_[j] + 2.f * gw_[j + 1] + gw_[j + 2]; // s_h g_w
        }

        // ---- finish d-axis for center plane p-1 (a = p-2, b = p-1, n = p) ----
        if (it >= 2 && active) {
            #pragma unroll
            for (int j = 0; j < 4; ++j) {
                float gx = a0[j] - n0[j];                    // g_d s_h s_w
                float gy = a1[j] + 2.f * b1[j] + n1[j];      // s_d g_h s_w
                float gz = a2[j] + 2.f * b2[j] + n2[j];      // s_d s_h g_w
                acc = fmaf(gx, gx, acc);
                acc = fmaf(gy, gy, acc);
                acc = fmaf(gz, gz, acc);
            }
        }

        // ---- rotate history (static register copies) ----
        #pragma unroll
        for (int j = 0; j < 4; ++j) {
            a0[j] = b0[j]; a1[j] = b1[j]; a2[j] = b2[j];
            b0[j] = n0[j]; b1[j] = n1[j]; b2[j] = n2[j];
        }
    }

    // ---- block reduction ----
    #pragma unroll
    for (int off = 32; off > 0; off >>= 1)
        acc += __shfl_down(acc, off, 64);
    if (tx == 0) wsum[ty] = acc;
    __syncthreads();
    if (tid == 0) {
        float s = (wsum[0] + wsum[1]) + (wsum[2] + wsum[3]);
        atomicAdd(out, s * SCALE);
    }
}

extern "C" void kernel_launch(void* const* d_in, const int* in_sizes, int n_in,
                              void* d_out, int out_size, void* d_ws, size_t ws_size,
                              hipStream_t stream) {
    const float* x = (const float*)d_in[0];
    const float* y = (const float*)d_in[1];
    float* out = (float*)d_out;

    hipMemsetAsync(out, 0, sizeof(float), stream);

    dim3 block(TW, 256 / TW);                 // 64 x 4
    dim3 grid((W_ + TW - 1) / TW,             // 4
              H_ / TH,                        // 12
              N_ * (D_ / TD));                // 40
    grad_loss_kernel<<<grid, block, 0, stream>>>(x, y, out);
}

// Round 4
// 151.960 us; speedup vs baseline: 1.4332x; 1.0013x over previous
//
#include <hip/hip_runtime.h>

// GradientLoss: sum_c mean( (conv3d_c(x) - conv3d_c(y))^2 ), c in {d,h,w} Sobel dirs.
// conv linear -> conv(x)-conv(y) = conv(x-y). Separable filters:
//   fx = g_d (x) s_h (x) s_w ; fy = s_d (x) g_h (x) s_w ; fz = s_d (x) s_h (x) g_w
// with s=[1,2,1], g=[1,0,-1]. SAME zero padding; squared output -> flip irrelevant.
//
// R3: software-pipeline staging. R2 serialized load->wait->LDS->barrier->compute
// (latency-bound, 2.4 TB/s). Now: loads for plane p+1 issue one iteration ahead
// into regs (nx/ny), compute runs BEFORE the LDS write, so each load has a
// write+barrier+compute window to land. TH 16->12 makes the halo tile exactly
// 252 float4 chunks -> one chunk per thread, staging addresses hoisted out of
// the d-loop.

#define N_  2
#define D_  160
#define H_  192
#define W_  224

#define TW  64   // tile width  (threads.x)
#define TH  12   // tile height (3 rows per thread.y)
#define TD  8    // d-chunk per block

constexpr int LROWS = TH + 2;       // 14
constexpr int LCW   = 18;           // float4 chunks per row
constexpr int LCOLS = LCW * 4;      // 72 floats per row (cols 3..68 used)
constexpr int NCHUNK = LROWS * LCW; // 252 chunks: one per thread
constexpr int PS = H_ * W_;         // plane stride
constexpr float SCALE = 1.0f / ((float)N_ * D_ * H_ * W_);

__global__ __launch_bounds__(256, 6)
void grad_loss_kernel(const float* __restrict__ x, const float* __restrict__ y,
                      float* __restrict__ out) {
    __shared__ float plane[2][LROWS][LCOLS];
    __shared__ float wsum[4];

    const int tx  = threadIdx.x;          // 0..63 -> w offset
    const int ty  = threadIdx.y;          // 0..3  -> 3 h-rows each
    const int tid = ty * 64 + tx;

    const int w0 = blockIdx.x * TW;
    const int h0 = blockIdx.y * TH;
    const int nchunks = D_ / TD;          // 20
    const int n  = blockIdx.z / nchunks;
    const int d0 = (blockIdx.z % nchunks) * TD;

    const size_t base = (size_t)n * D_ * PS;
    const bool active = (w0 + tx) < W_;   // last w-tile half-empty (224 = 3.5*64)

    // ---- staging assignment: one float4 chunk per thread, hoisted ----
    const bool stager = tid < NCHUNK;
    const int srow = tid / LCW;
    const int sci  = tid - srow * LCW;
    const int gh   = h0 - 1 + srow;
    const int gw0  = w0 - 4 + 4 * sci;                  // 16B aligned
    const bool sok = stager && (unsigned)gh < (unsigned)H_ &&
                     (unsigned)gw0 < (unsigned)W_;
    const float* px = x + base + (size_t)gh * W_ + gw0; // deref only when guarded
    const float* py = y + base + (size_t)gh * W_ + gw0;
    float* const ldst0 = &plane[0][0][0] + (srow * LCOLS + 4 * sci);
    float* const ldst1 = &plane[1][0][0] + (srow * LCOLS + 4 * sci);

    // statically-indexed 2-plane history (3 output rows per thread)
    float a0[3], a1[3], a2[3], b0[3], b1[3], b2[3];
    float acc = 0.f;
    const int rbase = 3 * ty;  // thread's first LDS row; uses rows rbase..rbase+4

    // ---- prologue: plane d0-1 -> buf0 ; issue plane d0 into rx/ry ----
    float4 rx = make_float4(0.f, 0.f, 0.f, 0.f), ry = rx;
    if (sok && d0 - 1 >= 0) {
        rx = *(const float4*)(px + (size_t)(d0 - 1) * PS);
        ry = *(const float4*)(py + (size_t)(d0 - 1) * PS);
    }
    if (stager)
        *(float4*)ldst0 = make_float4(rx.x - ry.x, rx.y - ry.y,
                                      rx.z - ry.z, rx.w - ry.w);
    rx = make_float4(0.f, 0.f, 0.f, 0.f); ry = rx;
    if (sok) {   // plane d0 always in [0,D)
        rx = *(const float4*)(px + (size_t)d0 * PS);
        ry = *(const float4*)(py + (size_t)d0 * PS);
    }

    for (int it = 0; it <= TD + 1; ++it) {
        __syncthreads();   // buf[it&1] (plane d0-1+it) ready; also orders the
                           // iter-(it-1) reads of buf[(it+1)&1] before our write
        float (*buf)[LCOLS] = plane[it & 1];

        // ---- in-plane stencils for this thread's 5 LDS rows ----
        float sw[5], gww[5];
        #pragma unroll
        for (int r = 0; r < 5; ++r) {
            float a = buf[rbase + r][tx + 3];
            float b = buf[rbase + r][tx + 4];
            float c = buf[rbase + r][tx + 5];
            sw[r]  = a + 2.f * b + c;   // s_w
            gww[r] = a - c;             // g_w
        }
        float n0[3], n1[3], n2[3];
        #pragma unroll
        for (int j = 0; j < 3; ++j) {
            n0[j] = sw[j] + 2.f * sw[j + 1] + sw[j + 2];    // s_h s_w
            n1[j] = sw[j] - sw[j + 2];                      // g_h s_w
            n2[j] = gww[j] + 2.f * gww[j + 1] + gww[j + 2]; // s_h g_w
        }

        // ---- finish d-axis for center plane (a = p-2, b = p-1, n = p) ----
        if (it >= 2 && active) {
            #pragma unroll
            for (int j = 0; j < 3; ++j) {
                float gx = a0[j] - n0[j];                    // g_d s_h s_w
                float gy = a1[j] + 2.f * b1[j] + n1[j];      // s_d g_h s_w
                float gz = a2[j] + 2.f * b2[j] + n2[j];      // s_d s_h g_w
                acc = fmaf(gx, gx, acc);
                acc = fmaf(gy, gy, acc);
                acc = fmaf(gz, gz, acc);
            }
        }

        // ---- rotate history ----
        #pragma unroll
        for (int j = 0; j < 3; ++j) {
            a0[j] = b0[j]; a1[j] = b1[j]; a2[j] = b2[j];
            b0[j] = n0[j]; b1[j] = n1[j]; b2[j] = n2[j];
        }

        // ---- pipeline: issue plane d0+it+1 loads, then write plane d0+it ----
        if (it < TD + 1) {
            float4 nx = make_float4(0.f, 0.f, 0.f, 0.f), ny = nx;
            if (it < TD) {
                int q = d0 + it + 1;
                if (sok && q < D_) {
                    nx = *(const float4*)(px + (size_t)q * PS);
                    ny = *(const float4*)(py + (size_t)q * PS);
                }
            }
            if (stager) {
                float* dst = (it & 1) ? ldst0 : ldst1;   // buf[(it+1)&1]
                *(float4*)dst = make_float4(rx.x - ry.x, rx.y - ry.y,
                                            rx.z - ry.z, rx.w - ry.w);
            }
            rx = nx; ry = ny;
        }
    }

    // ---- block reduction ----
    #pragma unroll
    for (int off = 32; off > 0; off >>= 1)
        acc += __shfl_down(acc, off, 64);
    if (tx == 0) wsum[ty] = acc;
    __syncthreads();
    if (tid == 0) {
        float s = (wsum[0] + wsum[1]) + (wsum[2] + wsum[3]);
        atomicAdd(out, s * SCALE);
    }
}

extern "C" void kernel_launch(void* const* d_in, const int* in_sizes, int n_in,
                              void* d_out, int out_size, void* d_ws, size_t ws_size,
                              hipStream_t stream) {
    const float* x = (const float*)d_in[0];
    const float* y = (const float*)d_in[1];
    float* out = (float*)d_out;

    hipMemsetAsync(out, 0, sizeof(float), stream);

    dim3 block(TW, 256 / TW);                 // 64 x 4
    dim3 grid((W_ + TW - 1) / TW,             // 4
              H_ / TH,                        // 16
              N_ * (D_ / TD));                // 40
    grad_loss_kernel<<<grid, block, 0, stream>>>(x, y, out);
}

// Round 5
// 149.613 us; speedup vs baseline: 1.4557x; 1.0157x over previous
//
#include <hip/hip_runtime.h>

// GradientLoss: sum_c mean( (conv3d_c(x) - conv3d_c(y))^2 ), c in {d,h,w} Sobel dirs.
// conv linear -> conv(x)-conv(y) = conv(x-y). Separable: s=[1,2,1], g=[1,0,-1];
// SAME zero pad; squared output -> flip irrelevant.
//
// R4: barrier-free. R2/R3's stage->__syncthreads->compute loop forces
// s_waitcnt vmcnt(0) every plane for every wave (latency-bound at 2.4 TB/s).
// New decomposition: NO LDS, NO barriers in the d-loop.
//   w-exchange: __shfl_up/down (lane = w; 62 outputs per 64-lane wave, edge
//               lanes are halo-only)
//   h-exchange: each lane owns 4 h-rows, loads its 6-row window redundantly
//               (halo rows L1/L3-served; whole volume < 256 MiB L3)
//   d-exchange: rolling 3-plane register history, fully unrolled (TD=8)
// Loads are 1-plane-ahead (xn/yn regs) so they stay in flight across the
// compute phase with fine-grained vmcnt only.

#define N_  2
#define D_  160
#define H_  192
#define W_  224
#define PS  (H_ * W_)          // plane stride = 43008

#define TD   8                 // d-planes computed per block
#define WOUT 62                // w outputs per wave (lanes 1..62)

constexpr float SCALE = 1.0f / ((float)N_ * D_ * H_ * W_);

__global__ __launch_bounds__(256, 6)
void grad_loss_kernel(const float* __restrict__ x, const float* __restrict__ y,
                      float* __restrict__ out) {
    __shared__ float wsum[4];

    const int tid  = threadIdx.x;
    const int lane = tid & 63;
    const int wv   = tid >> 6;

    const int w  = blockIdx.x * WOUT + lane - 1;      // lane 0 / 63 = w-halo
    const int h0 = blockIdx.y * 16 + wv * 4;          // wave's first output row
    const int nchunks = D_ / TD;                      // 20
    const int nb = blockIdx.z / nchunks;
    const int d0 = (blockIdx.z % nchunks) * TD;

    const bool wok    = (unsigned)w < (unsigned)W_;
    const bool active = (lane >= 1) && (lane <= 62) && wok;

    bool hv[6];
    #pragma unroll
    for (int r = 0; r < 6; ++r)
        hv[r] = (unsigned)(h0 - 1 + r) < (unsigned)H_;

    const float* bx = x + (size_t)nb * D_ * PS;
    const float* by = y + (size_t)nb * D_ * PS;
    const int obase = h0 * W_ + w;     // + p*PS + (r-1)*W_  (fits in int)

    float a0[4], a1[4], a2[4], b0[4], b1[4], b2[4];   // d-history (p-2, p-1)
    float vc[6];                                       // current plane window
    float acc = 0.f;

    // ---- prologue: plane d0-1 ----
    {
        const int p = d0 - 1;
        const bool pin = p >= 0;
        #pragma unroll
        for (int r = 0; r < 6; ++r) {
            float xv = 0.f, yv = 0.f;
            if (pin && hv[r] && wok) {
                int o = obase + p * PS + (r - 1) * W_;
                xv = bx[o]; yv = by[o];
            }
            vc[r] = xv - yv;
        }
    }

    #pragma unroll
    for (int it = 0; it <= TD + 1; ++it) {
        // ---- 1. issue plane (d0+it) loads into regs (land during compute) ----
        float xn[6], yn[6];
        const int p = d0 + it;
        const bool pref = (it <= TD) && (p < D_);
        #pragma unroll
        for (int r = 0; r < 6; ++r) {
            xn[r] = 0.f; yn[r] = 0.f;
            if (pref && hv[r] && wok) {
                int o = obase + p * PS + (r - 1) * W_;
                xn[r] = bx[o]; yn[r] = by[o];
            }
        }

        // ---- 2. in-plane stencils on vc (plane d0-1+it) ----
        float sw[6], gw[6];
        #pragma unroll
        for (int r = 0; r < 6; ++r) {
            float L  = __shfl_up(vc[r], 1, 64);    // v at w-1
            float Rt = __shfl_down(vc[r], 1, 64);  // v at w+1
            sw[r] = (L + Rt) + 2.f * vc[r];        // s_w
            gw[r] = L - Rt;                        // g_w
        }
        float n0[4], n1[4], n2[4];
        #pragma unroll
        for (int j = 0; j < 4; ++j) {
            n0[j] = sw[j] + 2.f * sw[j + 1] + sw[j + 2];   // s_h s_w
            n1[j] = sw[j] - sw[j + 2];                     // g_h s_w
            n2[j] = gw[j] + 2.f * gw[j + 1] + gw[j + 2];   // s_h g_w
        }

        // ---- 3. d-combine for center plane (a=p-2, b=p-1, n=p) ----
        if (it >= 2 && active) {
            #pragma unroll
            for (int j = 0; j < 4; ++j) {
                float gx = a0[j] - n0[j];                     // g_d s_h s_w
                float gy = a1[j] + 2.f * b1[j] + n1[j];       // s_d g_h s_w
                float gz = a2[j] + 2.f * b2[j] + n2[j];       // s_d s_h g_w
                acc = fmaf(gx, gx, acc);
                acc = fmaf(gy, gy, acc);
                acc = fmaf(gz, gz, acc);
            }
        }

        // ---- 4. rotate history (renamed away by full unroll) ----
        #pragma unroll
        for (int j = 0; j < 4; ++j) {
            a0[j] = b0[j]; a1[j] = b1[j]; a2[j] = b2[j];
            b0[j] = n0[j]; b1[j] = n1[j]; b2[j] = n2[j];
        }

        // ---- 5. commit prefetched plane (first use -> vmcnt wait here) ----
        #pragma unroll
        for (int r = 0; r < 6; ++r) vc[r] = xn[r] - yn[r];
    }

    // ---- reduction: wave butterfly, tiny LDS combine, one atomic/block ----
    #pragma unroll
    for (int off = 32; off > 0; off >>= 1)
        acc += __shfl_xor(acc, off, 64);
    if (lane == 0) wsum[wv] = acc;
    __syncthreads();
    if (tid == 0) {
        float s = (wsum[0] + wsum[1]) + (wsum[2] + wsum[3]);
        atomicAdd(out, s * SCALE);
    }
}

extern "C" void kernel_launch(void* const* d_in, const int* in_sizes, int n_in,
                              void* d_out, int out_size, void* d_ws, size_t ws_size,
                              hipStream_t stream) {
    const float* x = (const float*)d_in[0];
    const float* y = (const float*)d_in[1];
    float* out = (float*)d_out;

    hipMemsetAsync(out, 0, sizeof(float), stream);

    dim3 block(256);
    dim3 grid((W_ + WOUT - 1) / WOUT,   // 4 (62-wide strips, overlap-masked)
              H_ / 16,                  // 12 (block = 4 waves x 4 rows)
              N_ * (D_ / TD));          // 40
    grad_loss_kernel<<<grid, block, 0, stream>>>(x, y, out);
}